// Round 3
// baseline (1209.414 us; speedup 1.0000x reference)
//
#include <hip/hip_runtime.h>

#define CIN 64
#define COUT 128
#define TM 64   // output rows per conv tile

typedef __bf16 bf16x8 __attribute__((ext_vector_type(8)));
typedef float  f32x4  __attribute__((ext_vector_type(4)));

// ---------------------------------------------------------------------------
// Prep: features fp32 -> bf16 rows.
// ---------------------------------------------------------------------------
__global__ __launch_bounds__(256) void prep_feats_kernel(
    const float* __restrict__ feats, __bf16* __restrict__ fb, int total8)
{
    const int i = blockIdx.x * 256 + threadIdx.x;
    if (i >= total8) return;
    const int i8 = i * 8;
    const float4 x0 = *(const float4*)(feats + i8);
    const float4 x1 = *(const float4*)(feats + i8 + 4);
    bf16x8 v;
    v[0] = (__bf16)x0.x; v[1] = (__bf16)x0.y; v[2] = (__bf16)x0.z; v[3] = (__bf16)x0.w;
    v[4] = (__bf16)x1.x; v[5] = (__bf16)x1.y; v[6] = (__bf16)x1.z; v[7] = (__bf16)x1.w;
    *(bf16x8*)(fb + i8) = v;
}

// ---------------------------------------------------------------------------
// Prep: pack W_conv (9 taps) + W_skip into MFMA B-fragment layout.
// Frag f: taps f/16 (f<144), skip otherwise; within: c=rem>>1 (col-tile), s=rem&1 (k-step).
// Lane l of frag holds B[s*32+(l>>4)*8+j][c*16+(l&15)], j=0..7.
// ---------------------------------------------------------------------------
__global__ __launch_bounds__(256) void prep_wfrag_kernel(
    const float* __restrict__ Wc, const float* __restrict__ Ws,
    __bf16* __restrict__ wf)
{
    const int id = blockIdx.x * 256 + threadIdx.x;
    if (id >= 160 * 64) return;
    const int f = id >> 6, lane = id & 63;
    const float* W;
    int r;
    if (f < 144) { W = Wc + (size_t)(f >> 4) * CIN * COUT; r = f & 15; }
    else         { W = Ws;                                  r = f - 144; }
    const int c = r >> 1, s = r & 1;
    const int kbase = s * 32 + (lane >> 4) * 8;
    const int col = c * 16 + (lane & 15);
    bf16x8 v;
#pragma unroll
    for (int j = 0; j < 8; ++j) v[j] = (__bf16)W[(size_t)(kbase + j) * COUT + col];
    *(bf16x8*)(wf + ((size_t)f * 64 + lane) * 8) = v;
}

// ---------------------------------------------------------------------------
// Range table: lo_tab[k][t] = lower_bound(cout_idx[k], min(t*TM, M)).
// ---------------------------------------------------------------------------
__global__ __launch_bounds__(256) void range_kernel(
    const int* __restrict__ cout_idx, int* __restrict__ lo_tab,
    int ntiles, int M, int P)
{
    const int id = blockIdx.x * 256 + threadIdx.x;
    const int nt1 = ntiles + 1;
    if (id >= 9 * nt1) return;
    const int k = id / nt1;
    const int t = id - k * nt1;
    int target = t * TM; if (target > M) target = M;
    const int* __restrict__ c = cout_idx + (size_t)k * P;
    int lo = 0, hi = P;
    while (lo < hi) { const int mid = (lo + hi) >> 1; if (c[mid] < target) lo = mid + 1; else hi = mid; }
    lo_tab[(size_t)k * nt1 + t] = lo;
}

__global__ __launch_bounds__(256) void inv_kernel(
    const int* __restrict__ sout, int* __restrict__ inv, int Ls)
{
    const int i = blockIdx.x * 256 + threadIdx.x;
    if (i < Ls) inv[sout[i]] = i;
}

// ---------------------------------------------------------------------------
// Conv via MFMA. Block owns rows [m0, m0+TM); 4 waves column-split (2 col-tiles
// each) and walk the same 16-entry groups. D frag (col=lane&15, row=(lane>>4)*4+j)
// scatter-added into swizzled LDS acc. Fused BN partial stats.
// ---------------------------------------------------------------------------
__global__ __launch_bounds__(256, 2) void conv_mfma_kernel(
    const __bf16* __restrict__ fb, const __bf16* __restrict__ wf,
    const int* __restrict__ cin_idx, const int* __restrict__ cout_idx,
    const int* __restrict__ lo_tab, const int* __restrict__ boo,
    float* __restrict__ out,
    float* __restrict__ S0, float* __restrict__ S1, float* __restrict__ Q,
    int ntiles, int M, int P)
{
    __shared__ float acc[TM * COUT];
    __shared__ float red[256][3];
    const int t = threadIdx.x, lane = t & 63, wv = t >> 6;
    const int tile = blockIdx.x, m0 = tile * TM, nt1 = ntiles + 1;
    const int arow = lane & 15, apart = lane >> 4;
    const int c0t = wv * 2;                 // this wave's first col-tile
    const int colA = c0t * 16 + arow;
    const int colB = colA + 16;

    for (int idx = t; idx < TM * COUT; idx += 256) acc[idx] = 0.f;
    __syncthreads();

    for (int k = 0; k < 9; ++k) {
        const __bf16* wk = wf + ((size_t)k * 16 * 64 + lane) * 8;
        const bf16x8 b00 = *(const bf16x8*)(wk + (size_t)(c0t * 2 + 0) * 512);
        const bf16x8 b01 = *(const bf16x8*)(wk + (size_t)(c0t * 2 + 1) * 512);
        const bf16x8 b10 = *(const bf16x8*)(wk + (size_t)(c0t * 2 + 2) * 512);
        const bf16x8 b11 = *(const bf16x8*)(wk + (size_t)(c0t * 2 + 3) * 512);

        const int lo = lo_tab[k * nt1 + tile];
        const int hi = lo_tab[k * nt1 + tile + 1];
        const int* __restrict__ cik = cin_idx + (size_t)k * P;
        const int* __restrict__ cok = cout_idx + (size_t)k * P;

        for (int e0 = lo; e0 < hi; e0 += 16) {
            const int ea = e0 + arow;
            const int ii = (ea < hi) ? cik[ea] : 0;
            const __bf16* fr = fb + (size_t)ii * CIN + apart * 8;
            const bf16x8 a0 = *(const bf16x8*)fr;
            const bf16x8 a1 = *(const bf16x8*)(fr + 32);
            const int er = e0 + apart * 4;
            int rr[4];
#pragma unroll
            for (int j = 0; j < 4; ++j) rr[j] = (er + j < hi) ? (cok[er + j] - m0) : 0;

            f32x4 d0 = {0.f, 0.f, 0.f, 0.f};
            f32x4 d1 = {0.f, 0.f, 0.f, 0.f};
            d0 = __builtin_amdgcn_mfma_f32_16x16x32_bf16(a0, b00, d0, 0, 0, 0);
            d0 = __builtin_amdgcn_mfma_f32_16x16x32_bf16(a1, b01, d0, 0, 0, 0);
            d1 = __builtin_amdgcn_mfma_f32_16x16x32_bf16(a0, b10, d1, 0, 0, 0);
            d1 = __builtin_amdgcn_mfma_f32_16x16x32_bf16(a1, b11, d1, 0, 0, 0);

#pragma unroll
            for (int j = 0; j < 4; ++j) {
                if (er + j < hi) {
                    const int row = rr[j];
                    const int sw = (row & 1) << 4;   // parity swizzle: 4-way -> 2-way bank
                    atomicAdd(&acc[row * COUT + (colA ^ sw)], d0[j]);
                    atomicAdd(&acc[row * COUT + (colB ^ sw)], d1[j]);
                }
            }
        }
    }
    __syncthreads();

    // write rows once + fused BN partial stats
    const int ch = t & 127, rg = t >> 7;
    float s0 = 0.f, s1 = 0.f, q = 0.f;
    for (int r = rg; r < TM; r += 2) {
        const int m = m0 + r;
        if (m >= M) break;
        const float v = acc[r * COUT + (ch ^ ((r & 1) << 4))];
        out[(size_t)m * COUT + ch] = v;
        if (boo[m]) s1 += v; else s0 += v;
        q += v * v;
    }
    red[t][0] = s0; red[t][1] = s1; red[t][2] = q;
    __syncthreads();
    if (t < 128) {
        atomicAdd(&S0[ch], red[t][0] + red[t + 128][0]);
        atomicAdd(&S1[ch], red[t][1] + red[t + 128][1]);
        atomicAdd(&Q[ch],  red[t][2] + red[t + 128][2]);
    }
}

// ---------------------------------------------------------------------------
// Skip path via MFMA: dense gather-GEMM [Ls x 64] x [64 x 128] -> G, + stats.
// ---------------------------------------------------------------------------
__global__ __launch_bounds__(256, 2) void skip_mfma_kernel(
    const __bf16* __restrict__ fb, const __bf16* __restrict__ wf,
    const int* __restrict__ sin_idx,
    float* __restrict__ G, float* __restrict__ skS, float* __restrict__ skQ,
    int Ls)
{
    const int t = threadIdx.x, lane = t & 63, wv = t >> 6;
    const int arow = lane & 15, apart = lane >> 4;

    bf16x8 b[16];
    const __bf16* wk = wf + ((size_t)144 * 64 + lane) * 8;
#pragma unroll
    for (int fidx = 0; fidx < 16; ++fidx) b[fidx] = *(const bf16x8*)(wk + (size_t)fidx * 512);

    float s1[8], s2[8];
#pragma unroll
    for (int c = 0; c < 8; ++c) { s1[c] = 0.f; s2[c] = 0.f; }

    const int ngroups = (Ls + 15) >> 4;
    for (int g = blockIdx.x * 4 + wv; g < ngroups; g += gridDim.x * 4) {
        const int e0 = g * 16;
        const int ea = e0 + arow;
        const int ii = (ea < Ls) ? sin_idx[ea] : 0;
        const __bf16* fr = fb + (size_t)ii * CIN + apart * 8;
        const bf16x8 a0 = *(const bf16x8*)fr;
        const bf16x8 a1 = *(const bf16x8*)(fr + 32);
        const int er = e0 + apart * 4;
#pragma unroll
        for (int c = 0; c < 8; ++c) {
            f32x4 d = {0.f, 0.f, 0.f, 0.f};
            d = __builtin_amdgcn_mfma_f32_16x16x32_bf16(a0, b[c * 2 + 0], d, 0, 0, 0);
            d = __builtin_amdgcn_mfma_f32_16x16x32_bf16(a1, b[c * 2 + 1], d, 0, 0, 0);
            const int col = c * 16 + arow;
#pragma unroll
            for (int j = 0; j < 4; ++j) {
                if (er + j < Ls) {
                    const float v = d[j];
                    G[(size_t)(er + j) * COUT + col] = v;
                    s1[c] += v;
                    s2[c] += v * v;
                }
            }
        }
    }
#pragma unroll
    for (int c = 0; c < 8; ++c) {
        atomicAdd(&skS[c * 16 + arow], s1[c]);
        atomicAdd(&skQ[c * 16 + arow], s2[c]);
    }
}

// ---------------------------------------------------------------------------
// Single-block: BN params (main + skip), batch counts via bsearch, SE MLP.
// ---------------------------------------------------------------------------
__global__ __launch_bounds__(128) void params_kernel(
    const float* __restrict__ S0, const float* __restrict__ S1,
    const float* __restrict__ Q,
    const float* __restrict__ skS, const float* __restrict__ skQ,
    const int* __restrict__ boo,
    const float* __restrict__ gamma, const float* __restrict__ beta,
    const float* __restrict__ sgamma, const float* __restrict__ sbeta,
    const float* __restrict__ fc1, const float* __restrict__ fc2,
    float* __restrict__ scale, float* __restrict__ shift,
    float* __restrict__ sscale, float* __restrict__ sshift,
    float* __restrict__ attn,
    int Ls, int M)
{
    __shared__ float desc[2][COUT];
    __shared__ float hid[2][8];
    __shared__ float c0s;
    const int ch = threadIdx.x;

    if (ch == 0) {
        int lo = 0, hi = M;
        while (lo < hi) { const int mid = (lo + hi) >> 1; if (boo[mid] < 1) lo = mid + 1; else hi = mid; }
        c0s = (float)lo;
    }
    __syncthreads();
    const float c0 = c0s, c1 = (float)M - c0;
    const float Mf = (float)M;
    const float s0 = S0[ch], s1 = S1[ch];
    const float mu  = (s0 + s1) / Mf;
    const float var = Q[ch] / Mf - mu * mu;
    const float rs  = rsqrtf(var + 1e-5f);
    const float sc  = rs * gamma[ch];
    const float sh  = beta[ch] - mu * sc;
    scale[ch] = sc;
    shift[ch] = sh;
    desc[0][ch] = (s0 / c0) * sc + sh;
    desc[1][ch] = (s1 / c1) * sc + sh;

    const float lsf  = (float)Ls;
    const float mus  = skS[ch] / lsf;
    const float vars = skQ[ch] / lsf - mus * mus;
    const float rss  = rsqrtf(vars + 1e-5f);
    const float ssc  = rss * sgamma[ch];
    sscale[ch] = ssc;
    sshift[ch] = sbeta[ch] - mus * ssc;

    __syncthreads();
    if (ch < 16) {
        const int b = ch >> 3, h = ch & 7;
        float a = 0.f;
        for (int c = 0; c < COUT; ++c) a += desc[b][c] * fc1[c * 8 + h];
        hid[b][h] = fmaxf(a, 0.f);
    }
    __syncthreads();
    for (int b = 0; b < 2; ++b) {
        float a = 0.f;
        for (int h = 0; h < 8; ++h) a += hid[b][h] * fc2[h * COUT + ch];
        attn[b * COUT + ch] = 1.f / (1.f + expf(-a));
    }
}

// ---------------------------------------------------------------------------
// Epilogue: out = relu(bn(x)*attn[b] + bn_skip(G[inv])), float4-vectorized.
// ---------------------------------------------------------------------------
__global__ __launch_bounds__(256) void final_kernel(
    float* __restrict__ out,
    const float* __restrict__ G,
    const int* __restrict__ inv_skip,
    const int* __restrict__ batch_of_out,
    const float* __restrict__ scale, const float* __restrict__ shift,
    const float* __restrict__ sscale, const float* __restrict__ sshift,
    const float* __restrict__ attn,
    int M)
{
    const int t  = threadIdx.x;
    const int c4 = (t & 31) * 4;
    const int rw = t >> 5;                // 8 rows per block-iter
    const float4 sc  = *(const float4*)&scale[c4];
    const float4 sh  = *(const float4*)&shift[c4];
    const float4 ssc = *(const float4*)&sscale[c4];
    const float4 ssh = *(const float4*)&sshift[c4];
    const float4 at0 = *(const float4*)&attn[c4];
    const float4 at1 = *(const float4*)&attn[COUT + c4];

    for (int m = blockIdx.x * 8 + rw; m < M; m += gridDim.x * 8) {
        const float4 x = *(const float4*)&out[(size_t)m * COUT + c4];
        const int b = batch_of_out[m];
        const int j = inv_skip[m];
        const float4 av = b ? at1 : at0;
        float4 y;
        y.x = (x.x * sc.x + sh.x) * av.x;
        y.y = (x.y * sc.y + sh.y) * av.y;
        y.z = (x.z * sc.z + sh.z) * av.z;
        y.w = (x.w * sc.w + sh.w) * av.w;
        if (j >= 0) {
            const float4 g = *(const float4*)&G[(size_t)j * COUT + c4];
            y.x += g.x * ssc.x + ssh.x;
            y.y += g.y * ssc.y + ssh.y;
            y.z += g.z * ssc.z + ssh.z;
            y.w += g.w * ssc.w + ssh.w;
        }
        y.x = y.x > 0.f ? y.x : 0.f;
        y.y = y.y > 0.f ? y.y : 0.f;
        y.z = y.z > 0.f ? y.z : 0.f;
        y.w = y.w > 0.f ? y.w : 0.f;
        *(float4*)&out[(size_t)m * COUT + c4] = y;
    }
}

extern "C" void kernel_launch(void* const* d_in, const int* in_sizes, int n_in,
                              void* d_out, int out_size, void* d_ws, size_t ws_size,
                              hipStream_t stream)
{
    const float* feats  = (const float*)d_in[0];
    const float* Wc     = (const float*)d_in[1];
    const float* Wsk    = (const float*)d_in[2];
    const float* gamma  = (const float*)d_in[3];
    const float* beta   = (const float*)d_in[4];
    const float* sgamma = (const float*)d_in[5];
    const float* sbeta  = (const float*)d_in[6];
    const float* fc1    = (const float*)d_in[7];
    const float* fc2    = (const float*)d_in[8];
    const int* cin_idx  = (const int*)d_in[9];
    const int* cout_idx = (const int*)d_in[10];
    const int* sin_idx  = (const int*)d_in[11];
    const int* sout_idx = (const int*)d_in[12];
    const int* boo      = (const int*)d_in[13];

    const int N  = in_sizes[0] / CIN;
    const int P  = in_sizes[9] / 9;
    const int Ls = in_sizes[11];
    const int M  = in_sizes[13];
    const int ntiles = (M + TM - 1) / TM;

    float* out = (float*)d_out;

    // workspace layout
    char* ws = (char*)d_ws;
    __bf16* fb = (__bf16*)ws;
    size_t off = (size_t)N * CIN * sizeof(__bf16);
    off = (off + 255) & ~(size_t)255;
    __bf16* wfrag = (__bf16*)(ws + off);
    off += (size_t)160 * 64 * 8 * sizeof(__bf16);
    off = (off + 255) & ~(size_t)255;
    float* G = (float*)(ws + off);
    off += (size_t)Ls * COUT * sizeof(float);
    int* inv_skip = (int*)(ws + off);
    off += (size_t)M * sizeof(int);
    off = (off + 255) & ~(size_t)255;
    int* lo_tab = (int*)(ws + off);
    off += (size_t)9 * (ntiles + 1) * sizeof(int);
    off = (off + 255) & ~(size_t)255;
    float* stats = (float*)(ws + off);
    float* S0 = stats, *S1 = stats + 128, *Q = stats + 256;
    float* skS = stats + 384, *skQ = stats + 512;
    float* params = stats + 704;
    float* scale = params, *shift = params + 128;
    float* sscale = params + 256, *sshift = params + 384, *attn = params + 512;

    hipMemsetAsync(stats, 0, 704 * sizeof(float), stream);
    hipMemsetAsync(inv_skip, 0xFF, (size_t)M * sizeof(int), stream);  // -1

    const int total8 = N * CIN / 8;
    prep_feats_kernel<<<(total8 + 255) / 256, 256, 0, stream>>>(feats, fb, total8);
    prep_wfrag_kernel<<<(160 * 64 + 255) / 256, 256, 0, stream>>>(Wc, Wsk, wfrag);

    const int nrange = 9 * (ntiles + 1);
    range_kernel<<<(nrange + 255) / 256, 256, 0, stream>>>(cout_idx, lo_tab, ntiles, M, P);
    inv_kernel<<<(Ls + 255) / 256, 256, 0, stream>>>(sout_idx, inv_skip, Ls);

    conv_mfma_kernel<<<ntiles, 256, 0, stream>>>(
        fb, wfrag, cin_idx, cout_idx, lo_tab, boo, out, S0, S1, Q, ntiles, M, P);

    skip_mfma_kernel<<<512, 256, 0, stream>>>(
        fb, wfrag, sin_idx, G, skS, skQ, Ls);

    params_kernel<<<1, 128, 0, stream>>>(
        S0, S1, Q, skS, skQ, boo, gamma, beta, sgamma, sbeta, fc1, fc2,
        scale, shift, sscale, sshift, attn, Ls, M);

    final_kernel<<<2048, 256, 0, stream>>>(
        out, G, inv_skip, boo, scale, shift, sscale, sshift, attn, M);
}

// Round 4
// 459.157 us; speedup vs baseline: 2.6340x; 2.6340x over previous
//
#include <hip/hip_runtime.h>

#define CIN 64
#define COUT 128
#define TM 64     // output rows per conv tile
#define NB 32     // stat buckets (contention spreading)

typedef __bf16 bf16x8 __attribute__((ext_vector_type(8)));
typedef float  f32x4  __attribute__((ext_vector_type(4)));

// ---------------------------------------------------------------------------
// Prep: features fp32 -> bf16 rows.
// ---------------------------------------------------------------------------
__global__ __launch_bounds__(256) void prep_feats_kernel(
    const float* __restrict__ feats, __bf16* __restrict__ fb, int total8)
{
    const int i = blockIdx.x * 256 + threadIdx.x;
    if (i >= total8) return;
    const int i8 = i * 8;
    const float4 x0 = *(const float4*)(feats + i8);
    const float4 x1 = *(const float4*)(feats + i8 + 4);
    bf16x8 v;
    v[0] = (__bf16)x0.x; v[1] = (__bf16)x0.y; v[2] = (__bf16)x0.z; v[3] = (__bf16)x0.w;
    v[4] = (__bf16)x1.x; v[5] = (__bf16)x1.y; v[6] = (__bf16)x1.z; v[7] = (__bf16)x1.w;
    *(bf16x8*)(fb + i8) = v;
}

// ---------------------------------------------------------------------------
// Prep: pack W_conv (9 taps) + W_skip into MFMA B-fragment layout.
// Frag f: tap f/16 (f<144), skip otherwise; rem: c=rem>>1 (col-tile), s=rem&1 (k-step).
// Lane l holds B[s*32+(l>>4)*8+j][c*16+(l&15)], j=0..7.
// ---------------------------------------------------------------------------
__global__ __launch_bounds__(256) void prep_wfrag_kernel(
    const float* __restrict__ Wc, const float* __restrict__ Ws,
    __bf16* __restrict__ wf)
{
    const int id = blockIdx.x * 256 + threadIdx.x;
    if (id >= 160 * 64) return;
    const int f = id >> 6, lane = id & 63;
    const float* W;
    int r;
    if (f < 144) { W = Wc + (size_t)(f >> 4) * CIN * COUT; r = f & 15; }
    else         { W = Ws;                                  r = f - 144; }
    const int c = r >> 1, s = r & 1;
    const int kbase = s * 32 + (lane >> 4) * 8;
    const int col = c * 16 + (lane & 15);
    bf16x8 v;
#pragma unroll
    for (int j = 0; j < 8; ++j) v[j] = (__bf16)W[(size_t)(kbase + j) * COUT + col];
    *(bf16x8*)(wf + ((size_t)f * 64 + lane) * 8) = v;
}

// ---------------------------------------------------------------------------
// Range table: lo_tab[k][t] = lower_bound(cout_idx[k], min(t*TM, M)).
// ---------------------------------------------------------------------------
__global__ __launch_bounds__(256) void range_kernel(
    const int* __restrict__ cout_idx, int* __restrict__ lo_tab,
    int ntiles, int M, int P)
{
    const int id = blockIdx.x * 256 + threadIdx.x;
    const int nt1 = ntiles + 1;
    if (id >= 9 * nt1) return;
    const int k = id / nt1;
    const int t = id - k * nt1;
    int target = t * TM; if (target > M) target = M;
    const int* __restrict__ c = cout_idx + (size_t)k * P;
    int lo = 0, hi = P;
    while (lo < hi) { const int mid = (lo + hi) >> 1; if (c[mid] < target) lo = mid + 1; else hi = mid; }
    lo_tab[(size_t)k * nt1 + t] = lo;
}

__global__ __launch_bounds__(256) void inv_kernel(
    const int* __restrict__ sout, int* __restrict__ inv, int Ls)
{
    const int i = blockIdx.x * 256 + threadIdx.x;
    if (i < Ls) inv[sout[i]] = i;
}

// ---------------------------------------------------------------------------
// Conv via MFMA. Block owns rows [m0, m0+TM); 4 waves column-split (2 col-tiles
// each), walking the same 16-entry groups. D frag row j = group entry apart*4+j.
// Scatter-add into parity-swizzled LDS acc. Fused BN partial stats -> bucket.
// ---------------------------------------------------------------------------
__global__ __launch_bounds__(256, 2) void conv_mfma_kernel(
    const __bf16* __restrict__ fb, const __bf16* __restrict__ wf,
    const int* __restrict__ cin_idx, const int* __restrict__ cout_idx,
    const int* __restrict__ lo_tab, const int* __restrict__ boo,
    float* __restrict__ out, float* __restrict__ stats,
    int ntiles, int M, int P)
{
    __shared__ float acc[TM * COUT];
    __shared__ float red[256][3];
    const int t = threadIdx.x, lane = t & 63, wv = t >> 6;
    const int tile = blockIdx.x, m0 = tile * TM, nt1 = ntiles + 1;
    const int arow = lane & 15, apart = lane >> 4;
    const int c0t = wv * 2;
    const int colA = c0t * 16 + arow;
    const int colB = colA + 16;

    for (int idx = t; idx < TM * COUT; idx += 256) acc[idx] = 0.f;
    __syncthreads();

    for (int k = 0; k < 9; ++k) {
        const __bf16* wk = wf + ((size_t)k * 16 * 64 + lane) * 8;
        const bf16x8 b00 = *(const bf16x8*)(wk + (size_t)(c0t * 2 + 0) * 512);
        const bf16x8 b01 = *(const bf16x8*)(wk + (size_t)(c0t * 2 + 1) * 512);
        const bf16x8 b10 = *(const bf16x8*)(wk + (size_t)(c0t * 2 + 2) * 512);
        const bf16x8 b11 = *(const bf16x8*)(wk + (size_t)(c0t * 2 + 3) * 512);

        const int lo = lo_tab[k * nt1 + tile];
        const int hi = lo_tab[k * nt1 + tile + 1];
        const int* __restrict__ cik = cin_idx + (size_t)k * P;
        const int* __restrict__ cok = cout_idx + (size_t)k * P;

        for (int e0 = lo; e0 < hi; e0 += 16) {
            const int ea = e0 + arow;
            const int valid = ea < hi;
            const int ii = valid ? cik[ea] : 0;
            const int co = valid ? (cok[ea] - m0) : 0;   // coalesced; shuffled below
            const __bf16* fr = fb + (size_t)ii * CIN + apart * 8;
            const bf16x8 a0 = *(const bf16x8*)fr;
            const bf16x8 a1 = *(const bf16x8*)(fr + 32);

            f32x4 d0 = {0.f, 0.f, 0.f, 0.f};
            f32x4 d1 = {0.f, 0.f, 0.f, 0.f};
            d0 = __builtin_amdgcn_mfma_f32_16x16x32_bf16(a0, b00, d0, 0, 0, 0);
            d0 = __builtin_amdgcn_mfma_f32_16x16x32_bf16(a1, b01, d0, 0, 0, 0);
            d1 = __builtin_amdgcn_mfma_f32_16x16x32_bf16(a0, b10, d1, 0, 0, 0);
            d1 = __builtin_amdgcn_mfma_f32_16x16x32_bf16(a1, b11, d1, 0, 0, 0);

            const int er = e0 + apart * 4;
#pragma unroll
            for (int j = 0; j < 4; ++j) {
                const int row = __shfl(co, apart * 4 + j, 16);  // entry er+j's out-row
                if (er + j < hi) {
                    const int sw = (row & 1) << 4;   // parity swizzle: 4-way -> 2-way bank
                    atomicAdd(&acc[row * COUT + (colA ^ sw)], d0[j]);
                    atomicAdd(&acc[row * COUT + (colB ^ sw)], d1[j]);
                }
            }
        }
    }
    __syncthreads();

    // write rows once + fused BN partial stats
    const int ch = t & 127, rg = t >> 7;
    float s0 = 0.f, s1 = 0.f, q = 0.f;
    for (int r = rg; r < TM; r += 2) {
        const int m = m0 + r;
        if (m >= M) break;
        const float v = acc[r * COUT + (ch ^ ((r & 1) << 4))];
        out[(size_t)m * COUT + ch] = v;
        if (boo[m]) s1 += v; else s0 += v;
        q += v * v;
    }
    red[t][0] = s0; red[t][1] = s1; red[t][2] = q;
    __syncthreads();
    float* bucket = stats + (size_t)(blockIdx.x & (NB - 1)) * 640;
    if (t < 128) {
        atomicAdd(&bucket[t],       red[t][0] + red[t + 128][0]);
        atomicAdd(&bucket[128 + t], red[t][1] + red[t + 128][1]);
        atomicAdd(&bucket[256 + t], red[t][2] + red[t + 128][2]);
    }
}

// ---------------------------------------------------------------------------
// Skip path via MFMA, column-split waves (2 col-tiles each -> 4 B frags).
// Stats: shuffle-reduce over lane quarters, LDS combine, bucketed atomics.
// ---------------------------------------------------------------------------
__global__ __launch_bounds__(256, 2) void skip_mfma_kernel(
    const __bf16* __restrict__ fb, const __bf16* __restrict__ wf,
    const int* __restrict__ sin_idx,
    float* __restrict__ G, float* __restrict__ stats, int Ls)
{
    __shared__ float sk[2][COUT];
    const int t = threadIdx.x, lane = t & 63, wv = t >> 6;
    const int arow = lane & 15, apart = lane >> 4;

    const __bf16* wk = wf + ((size_t)144 * 64 + lane) * 8;
    const bf16x8 b00 = *(const bf16x8*)(wk + (size_t)(wv * 4 + 0) * 512);
    const bf16x8 b01 = *(const bf16x8*)(wk + (size_t)(wv * 4 + 1) * 512);
    const bf16x8 b10 = *(const bf16x8*)(wk + (size_t)(wv * 4 + 2) * 512);
    const bf16x8 b11 = *(const bf16x8*)(wk + (size_t)(wv * 4 + 3) * 512);
    const int colA = wv * 32 + arow;
    const int colB = colA + 16;

    float s1A = 0.f, s2A = 0.f, s1B = 0.f, s2B = 0.f;
    const int ngroups = (Ls + 15) >> 4;
    for (int g = blockIdx.x; g < ngroups; g += gridDim.x) {
        const int e0 = g * 16;
        const int ea = e0 + arow;
        const int ii = (ea < Ls) ? sin_idx[ea] : 0;
        const __bf16* fr = fb + (size_t)ii * CIN + apart * 8;
        const bf16x8 a0 = *(const bf16x8*)fr;
        const bf16x8 a1 = *(const bf16x8*)(fr + 32);

        f32x4 dA = {0.f, 0.f, 0.f, 0.f};
        f32x4 dB = {0.f, 0.f, 0.f, 0.f};
        dA = __builtin_amdgcn_mfma_f32_16x16x32_bf16(a0, b00, dA, 0, 0, 0);
        dA = __builtin_amdgcn_mfma_f32_16x16x32_bf16(a1, b01, dA, 0, 0, 0);
        dB = __builtin_amdgcn_mfma_f32_16x16x32_bf16(a0, b10, dB, 0, 0, 0);
        dB = __builtin_amdgcn_mfma_f32_16x16x32_bf16(a1, b11, dB, 0, 0, 0);

        const int er = e0 + apart * 4;
#pragma unroll
        for (int j = 0; j < 4; ++j) {
            if (er + j < Ls) {
                const float vA = dA[j], vB = dB[j];
                G[(size_t)(er + j) * COUT + colA] = vA;
                G[(size_t)(er + j) * COUT + colB] = vB;
                s1A += vA; s2A += vA * vA;
                s1B += vB; s2B += vB * vB;
            }
        }
    }
    // reduce over the 4 lane-quarters (lane bits 4,5)
    s1A += __shfl_xor(s1A, 16); s1A += __shfl_xor(s1A, 32);
    s2A += __shfl_xor(s2A, 16); s2A += __shfl_xor(s2A, 32);
    s1B += __shfl_xor(s1B, 16); s1B += __shfl_xor(s1B, 32);
    s2B += __shfl_xor(s2B, 16); s2B += __shfl_xor(s2B, 32);
    if (apart == 0) {
        sk[0][colA] = s1A; sk[0][colB] = s1B;
        sk[1][colA] = s2A; sk[1][colB] = s2B;
    }
    __syncthreads();
    float* bucket = stats + (size_t)(blockIdx.x & (NB - 1)) * 640;
    if (t < 128) {
        atomicAdd(&bucket[384 + t], sk[0][t]);
        atomicAdd(&bucket[512 + t], sk[1][t]);
    }
}

// ---------------------------------------------------------------------------
// Single-block: reduce stat buckets, BN params, batch counts, SE MLP.
// ---------------------------------------------------------------------------
__global__ __launch_bounds__(128) void params_kernel(
    const float* __restrict__ stats,
    const int* __restrict__ boo,
    const float* __restrict__ gamma, const float* __restrict__ beta,
    const float* __restrict__ sgamma, const float* __restrict__ sbeta,
    const float* __restrict__ fc1, const float* __restrict__ fc2,
    float* __restrict__ scale, float* __restrict__ shift,
    float* __restrict__ sscale, float* __restrict__ sshift,
    float* __restrict__ attn,
    int Ls, int M)
{
    __shared__ float desc[2][COUT];
    __shared__ float hid[2][8];
    __shared__ float c0s;
    const int ch = threadIdx.x;

    float s0 = 0.f, s1 = 0.f, q = 0.f, ss = 0.f, sq = 0.f;
    for (int b = 0; b < NB; ++b) {
        const float* st = stats + (size_t)b * 640;
        s0 += st[ch]; s1 += st[128 + ch]; q += st[256 + ch];
        ss += st[384 + ch]; sq += st[512 + ch];
    }

    if (ch == 0) {
        int lo = 0, hi = M;
        while (lo < hi) { const int mid = (lo + hi) >> 1; if (boo[mid] < 1) lo = mid + 1; else hi = mid; }
        c0s = (float)lo;
    }
    __syncthreads();
    const float c0 = c0s, c1 = (float)M - c0;
    const float Mf = (float)M;
    const float mu  = (s0 + s1) / Mf;
    const float var = q / Mf - mu * mu;
    const float rs  = rsqrtf(var + 1e-5f);
    const float sc  = rs * gamma[ch];
    const float sh  = beta[ch] - mu * sc;
    scale[ch] = sc;
    shift[ch] = sh;
    desc[0][ch] = (s0 / c0) * sc + sh;
    desc[1][ch] = (s1 / c1) * sc + sh;

    const float lsf  = (float)Ls;
    const float mus  = ss / lsf;
    const float vars = sq / lsf - mus * mus;
    const float rss  = rsqrtf(vars + 1e-5f);
    const float ssc  = rss * sgamma[ch];
    sscale[ch] = ssc;
    sshift[ch] = sbeta[ch] - mus * ssc;

    __syncthreads();
    if (ch < 16) {
        const int b = ch >> 3, h = ch & 7;
        float a = 0.f;
        for (int c = 0; c < COUT; ++c) a += desc[b][c] * fc1[c * 8 + h];
        hid[b][h] = fmaxf(a, 0.f);
    }
    __syncthreads();
    for (int b = 0; b < 2; ++b) {
        float a = 0.f;
        for (int h = 0; h < 8; ++h) a += hid[b][h] * fc2[h * COUT + ch];
        attn[b * COUT + ch] = 1.f / (1.f + expf(-a));
    }
}

// ---------------------------------------------------------------------------
// Epilogue: out = relu(bn(x)*attn[b] + bn_skip(G[inv])), float4-vectorized.
// ---------------------------------------------------------------------------
__global__ __launch_bounds__(256) void final_kernel(
    float* __restrict__ out,
    const float* __restrict__ G,
    const int* __restrict__ inv_skip,
    const int* __restrict__ batch_of_out,
    const float* __restrict__ scale, const float* __restrict__ shift,
    const float* __restrict__ sscale, const float* __restrict__ sshift,
    const float* __restrict__ attn,
    int M)
{
    const int t  = threadIdx.x;
    const int c4 = (t & 31) * 4;
    const int rw = t >> 5;
    const float4 sc  = *(const float4*)&scale[c4];
    const float4 sh  = *(const float4*)&shift[c4];
    const float4 ssc = *(const float4*)&sscale[c4];
    const float4 ssh = *(const float4*)&sshift[c4];
    const float4 at0 = *(const float4*)&attn[c4];
    const float4 at1 = *(const float4*)&attn[COUT + c4];

    for (int m = blockIdx.x * 8 + rw; m < M; m += gridDim.x * 8) {
        const float4 x = *(const float4*)&out[(size_t)m * COUT + c4];
        const int b = batch_of_out[m];
        const int j = inv_skip[m];
        const float4 av = b ? at1 : at0;
        float4 y;
        y.x = (x.x * sc.x + sh.x) * av.x;
        y.y = (x.y * sc.y + sh.y) * av.y;
        y.z = (x.z * sc.z + sh.z) * av.z;
        y.w = (x.w * sc.w + sh.w) * av.w;
        if (j >= 0) {
            const float4 g = *(const float4*)&G[(size_t)j * COUT + c4];
            y.x += g.x * ssc.x + ssh.x;
            y.y += g.y * ssc.y + ssh.y;
            y.z += g.z * ssc.z + ssh.z;
            y.w += g.w * ssc.w + ssh.w;
        }
        y.x = y.x > 0.f ? y.x : 0.f;
        y.y = y.y > 0.f ? y.y : 0.f;
        y.z = y.z > 0.f ? y.z : 0.f;
        y.w = y.w > 0.f ? y.w : 0.f;
        *(float4*)&out[(size_t)m * COUT + c4] = y;
    }
}

extern "C" void kernel_launch(void* const* d_in, const int* in_sizes, int n_in,
                              void* d_out, int out_size, void* d_ws, size_t ws_size,
                              hipStream_t stream)
{
    const float* feats  = (const float*)d_in[0];
    const float* Wc     = (const float*)d_in[1];
    const float* Wsk    = (const float*)d_in[2];
    const float* gamma  = (const float*)d_in[3];
    const float* beta   = (const float*)d_in[4];
    const float* sgamma = (const float*)d_in[5];
    const float* sbeta  = (const float*)d_in[6];
    const float* fc1    = (const float*)d_in[7];
    const float* fc2    = (const float*)d_in[8];
    const int* cin_idx  = (const int*)d_in[9];
    const int* cout_idx = (const int*)d_in[10];
    const int* sin_idx  = (const int*)d_in[11];
    const int* sout_idx = (const int*)d_in[12];
    const int* boo      = (const int*)d_in[13];

    const int N  = in_sizes[0] / CIN;
    const int P  = in_sizes[9] / 9;
    const int Ls = in_sizes[11];
    const int M  = in_sizes[13];
    const int ntiles = (M + TM - 1) / TM;

    float* out = (float*)d_out;

    // workspace layout
    char* ws = (char*)d_ws;
    __bf16* fb = (__bf16*)ws;
    size_t off = (size_t)N * CIN * sizeof(__bf16);
    off = (off + 255) & ~(size_t)255;
    __bf16* wfrag = (__bf16*)(ws + off);
    off += (size_t)160 * 64 * 8 * sizeof(__bf16);
    off = (off + 255) & ~(size_t)255;
    float* G = (float*)(ws + off);
    off += (size_t)Ls * COUT * sizeof(float);
    int* inv_skip = (int*)(ws + off);
    off += (size_t)M * sizeof(int);
    off = (off + 255) & ~(size_t)255;
    int* lo_tab = (int*)(ws + off);
    off += (size_t)9 * (ntiles + 1) * sizeof(int);
    off = (off + 255) & ~(size_t)255;
    float* stats = (float*)(ws + off);            // NB buckets x 640
    off += (size_t)NB * 640 * sizeof(float);
    float* params = (float*)(ws + off);
    float* scale = params, *shift = params + 128;
    float* sscale = params + 256, *sshift = params + 384, *attn = params + 512;

    hipMemsetAsync(stats, 0, (size_t)NB * 640 * sizeof(float), stream);
    hipMemsetAsync(inv_skip, 0xFF, (size_t)M * sizeof(int), stream);  // -1

    const int total8 = N * CIN / 8;
    prep_feats_kernel<<<(total8 + 255) / 256, 256, 0, stream>>>(feats, fb, total8);
    prep_wfrag_kernel<<<(160 * 64 + 255) / 256, 256, 0, stream>>>(Wc, Wsk, wfrag);

    const int nrange = 9 * (ntiles + 1);
    range_kernel<<<(nrange + 255) / 256, 256, 0, stream>>>(cout_idx, lo_tab, ntiles, M, P);
    inv_kernel<<<(Ls + 255) / 256, 256, 0, stream>>>(sout_idx, inv_skip, Ls);

    conv_mfma_kernel<<<ntiles, 256, 0, stream>>>(
        fb, wfrag, cin_idx, cout_idx, lo_tab, boo, out, stats, ntiles, M, P);

    skip_mfma_kernel<<<256, 256, 0, stream>>>(
        fb, wfrag, sin_idx, G, stats, Ls);

    params_kernel<<<1, 128, 0, stream>>>(
        stats, boo, gamma, beta, sgamma, sbeta, fc1, fc2,
        scale, shift, sscale, sshift, attn, Ls, M);

    final_kernel<<<2048, 256, 0, stream>>>(
        out, G, inv_skip, boo, scale, shift, sscale, sshift, attn, M);
}